// Round 11
// baseline (197.737 us; speedup 1.0000x reference)
//
#include <hip/hip_runtime.h>

typedef __bf16 bf16;
typedef __bf16 bf16x8 __attribute__((ext_vector_type(8)));
typedef float  f32x4  __attribute__((ext_vector_type(4)));

static constexpr int CB = 2;     // batch
static constexpr int CS = 2048;  // seq
static constexpr int CD = 512;   // model dim
static constexpr int CH = 8;     // heads
static constexpr int CDK = 64;   // head dim
static constexpr int NROWS = CB * CH * CS;         // 32768 attention rows
static constexpr size_t NT = (size_t)CB * CS * CD; // 2,097,152 elements per tensor
static constexpr size_t WN = (size_t)CD * CD;      // 262,144 weight elements

__device__ __forceinline__ f32x4 mfma16(bf16x8 a, bf16x8 b, f32x4 c) {
    return __builtin_amdgcn_mfma_f32_16x16x32_bf16(a, b, c, 0, 0, 0);
}

__device__ __forceinline__ bf16x8 cvt8(const float* __restrict__ p) {
    float4 x0 = *reinterpret_cast<const float4*>(p);
    float4 x1 = *reinterpret_cast<const float4*>(p + 4);
    bf16x8 r;
    r[0] = (bf16)x0.x; r[1] = (bf16)x0.y; r[2] = (bf16)x0.z; r[3] = (bf16)x0.w;
    r[4] = (bf16)x1.x; r[5] = (bf16)x1.y; r[6] = (bf16)x1.z; r[7] = (bf16)x1.w;
    return r;
}

__device__ __forceinline__ void gload16(const void* g, void* l) {
    __builtin_amdgcn_global_load_lds(
        (const __attribute__((address_space(1))) void*)g,
        (__attribute__((address_space(3))) void*)l, 16, 0, 0);
}

// ---- f32 -> bf16 conversion pass (inputs + weights) ----
struct CvtP {
    const float* src[10];
    bf16* dst[10];
    int n8[10];       // elements/8
};
__global__ __launch_bounds__(256) void cvt_kernel(CvtP C) {
    const int t = blockIdx.y;
    const int i = blockIdx.x * 256 + threadIdx.x;
    if (i < C.n8[t])
        *reinterpret_cast<bf16x8*>(C.dst[t] + (size_t)i * 8) =
            cvt8(C.src[t] + (size_t)i * 8);
}

// ---- merged projection GEMM (bf16 in), 64x64 tile, gload_lds dbuf ----
struct PB {
    const bf16* A[6];
    const bf16* W[6];
    const float* bias[6];
    bf16* dst[6];
    int mode[6];   // 0: [B,H,S,DK]   1: [B,H,DK,S]
};
__global__ __launch_bounds__(256) void projb_kernel(PB P) {
    __shared__ uint4 tile[2][2][512];   // [buf][A/B][row*8+slot] 32KB, XOR-swizzled

    const int z = blockIdx.z;
    const bf16* __restrict__ A = P.A[z];
    const bf16* __restrict__ W = P.W[z];
    const float* __restrict__ bias = P.bias[z];
    bf16* __restrict__ dst = P.dst[z];
    const int mode = P.mode[z];

    const int m0 = blockIdx.x * 64, n0 = blockIdx.y * 64;
    const int tid = threadIdx.x;
    const int lane = tid & 63, w = tid >> 6;
    const int wm = w >> 1, wn = w & 1;
    const int l16 = lane & 15, lhi = lane >> 4;

    const int tensor = w >> 1, half = w & 1;
    const int rlo = lane >> 3, slotL = lane & 7;
    const bf16* gbase = tensor ? W : A;
    const int t0 = tensor ? n0 : m0;
    const char* gp = (const char*)gbase
                   + (size_t)(t0 + half*32 + rlo) * (CD * 2)
                   + (size_t)((slotL ^ rlo) * 16);

    auto stage = [&](int buf, int kk) {
        const char* p = gp + (size_t)kk * 128;
        uint4* ld = &tile[buf][tensor][half * 256];
        #pragma unroll
        for (int i = 0; i < 4; ++i)
            gload16(p + (size_t)i * 8 * (CD * 2), ld + i * 64);
    };

    f32x4 acc[2][2] = {};

    stage(0, 0);
    asm volatile("s_waitcnt vmcnt(0)" ::: "memory");
    __syncthreads();

    for (int kk = 0; kk < 8; ++kk) {
        if (kk + 1 < 8) stage((kk + 1) & 1, kk + 1);

        const uint4* aT = &tile[kk & 1][0][0];
        const uint4* bT = &tile[kk & 1][1][0];
        #pragma unroll
        for (int ks = 0; ks < 2; ++ks) {
            const int c = ks*4 + lhi;
            const int ra0 = wm*32 + l16, ra1 = ra0 + 16;
            const int rb0 = wn*32 + l16, rb1 = rb0 + 16;
            bf16x8 af0 = __builtin_bit_cast(bf16x8, aT[ra0*8 + (c ^ (ra0 & 7))]);
            bf16x8 af1 = __builtin_bit_cast(bf16x8, aT[ra1*8 + (c ^ (ra1 & 7))]);
            bf16x8 bg0 = __builtin_bit_cast(bf16x8, bT[rb0*8 + (c ^ (rb0 & 7))]);
            bf16x8 bg1 = __builtin_bit_cast(bf16x8, bT[rb1*8 + (c ^ (rb1 & 7))]);
            acc[0][0] = mfma16(af0, bg0, acc[0][0]);
            acc[0][1] = mfma16(af0, bg1, acc[0][1]);
            acc[1][0] = mfma16(af1, bg0, acc[1][0]);
            acc[1][1] = mfma16(af1, bg1, acc[1][1]);
        }
        if (kk + 1 < 8) __syncthreads();
    }

    #pragma unroll
    for (int ms = 0; ms < 2; ++ms)
    #pragma unroll
    for (int ns = 0; ns < 2; ++ns) {
        const int col = n0 + wn*32 + ns*16 + l16;
        const float bv = bias[col];
        const int hh = col >> 6, dk = col & 63;
        #pragma unroll
        for (int i = 0; i < 4; ++i) {
            const int m = m0 + wm*32 + ms*16 + lhi*4 + i;
            const float v = acc[ms][ns][i] + bv;
            const int b = m >> 11, s = m & 2047;
            if (mode == 0)
                dst[(((size_t)(b*CH + hh)) * CS + s) * CDK + dk] = (bf16)v;
            else
                dst[(((size_t)(b*CH + hh)) * CDK + dk) * CS + s] = (bf16)v;
        }
    }
}

// ---- output GEMM (bf16 in), 64x64 tile, gload_lds dbuf. grid (64,8,2). ----
__global__ __launch_bounds__(256) void oprojb_kernel(
    const bf16* __restrict__ Xr, const bf16* __restrict__ Xp,
    const bf16* __restrict__ Wo, const float* __restrict__ bo,
    float* __restrict__ out)
{
    __shared__ uint4 tile[2][2][512];

    const bf16* __restrict__ A = blockIdx.z ? Xp : Xr;
    float* __restrict__ dst = out + (size_t)blockIdx.z * NT;

    const int m0 = blockIdx.x * 64, n0 = blockIdx.y * 64;
    const int tid = threadIdx.x;
    const int lane = tid & 63, w = tid >> 6;
    const int wm = w >> 1, wn = w & 1;
    const int l16 = lane & 15, lhi = lane >> 4;

    const int tensor = w >> 1, half = w & 1;
    const int rlo = lane >> 3, slotL = lane & 7;
    const bf16* gbase = tensor ? Wo : A;
    const int t0 = tensor ? n0 : m0;
    const char* gp = (const char*)gbase
                   + (size_t)(t0 + half*32 + rlo) * (CD * 2)
                   + (size_t)((slotL ^ rlo) * 16);

    auto stage = [&](int buf, int kk) {
        const char* p = gp + (size_t)kk * 128;
        uint4* ld = &tile[buf][tensor][half * 256];
        #pragma unroll
        for (int i = 0; i < 4; ++i)
            gload16(p + (size_t)i * 8 * (CD * 2), ld + i * 64);
    };

    f32x4 acc[2][2] = {};

    stage(0, 0);
    asm volatile("s_waitcnt vmcnt(0)" ::: "memory");
    __syncthreads();

    for (int kk = 0; kk < 8; ++kk) {
        if (kk + 1 < 8) stage((kk + 1) & 1, kk + 1);

        const uint4* aT = &tile[kk & 1][0][0];
        const uint4* bT = &tile[kk & 1][1][0];
        #pragma unroll
        for (int ks = 0; ks < 2; ++ks) {
            const int c = ks*4 + lhi;
            const int ra0 = wm*32 + l16, ra1 = ra0 + 16;
            const int rb0 = wn*32 + l16, rb1 = rb0 + 16;
            bf16x8 af0 = __builtin_bit_cast(bf16x8, aT[ra0*8 + (c ^ (ra0 & 7))]);
            bf16x8 af1 = __builtin_bit_cast(bf16x8, aT[ra1*8 + (c ^ (ra1 & 7))]);
            bf16x8 bg0 = __builtin_bit_cast(bf16x8, bT[rb0*8 + (c ^ (rb0 & 7))]);
            bf16x8 bg1 = __builtin_bit_cast(bf16x8, bT[rb1*8 + (c ^ (rb1 & 7))]);
            acc[0][0] = mfma16(af0, bg0, acc[0][0]);
            acc[0][1] = mfma16(af0, bg1, acc[0][1]);
            acc[1][0] = mfma16(af1, bg0, acc[1][0]);
            acc[1][1] = mfma16(af1, bg1, acc[1][1]);
        }
        if (kk + 1 < 8) __syncthreads();
    }

    #pragma unroll
    for (int ms = 0; ms < 2; ++ms)
    #pragma unroll
    for (int ns = 0; ns < 2; ++ns) {
        const int col = n0 + wn*32 + ns*16 + l16;
        const float bv = bo[col];
        #pragma unroll
        for (int i = 0; i < 4; ++i) {
            const int m = m0 + wm*32 + ms*16 + lhi*4 + i;
            dst[(size_t)m * 512 + col] = acc[ms][ns][i] + bv;
        }
    }
}

// ---- flash attention: 512 thr (8 waves), 16 q/wave, swapped QK^T, in-reg P.
// K fragments read DIRECTLY from global (L2-resident slab); only V staged in
// LDS (32KB dbuf via gload_lds). One __syncthreads per iter.
__global__ __launch_bounds__(512, 4) void attn_kernel(
    const bf16* __restrict__ Qr, const bf16* __restrict__ Qp,
    const bf16* __restrict__ Kr, const bf16* __restrict__ Kp,
    const bf16* __restrict__ Vtr, const bf16* __restrict__ Vtp,
    const int* __restrict__ mask, int lognsp,
    float* __restrict__ POR, float* __restrict__ POP, float* __restrict__ PLs)
{
    __shared__ uint4 vstg[2][2][512];   // [buf][Vtr,Vtp][row*8+slot] 32KB

    const int F = blockIdx.x;
    const int qt = (F >> 3) & 15;
    const int g  = (F & 7) | ((F >> 7) << 3);     // (bh,z) groups pinned per XCD
    const int bh = g >> lognsp, z = g & ((1 << lognsp) - 1);
    const int Lkv = CS >> lognsp, kvbase = z * Lkv;
    const int nt = Lkv >> 6;
    const int b = bh >> 3;
    const size_t base = (size_t)bh * CS * CDK;

    const int tid = threadIdx.x, lane = tid & 63, w = tid >> 6;
    const int l16 = lane & 15, lhi = lane >> 4;
    const int q0 = qt * 128 + w * 16;

    // V staging: wave w -> tensor (w&1), row-quarter (w>>1); 2 gload16 per wave
    const int vtensor = w & 1, quarter = w >> 1;
    const int rlo = lane >> 3, slotL = lane & 7;
    const int chunkL = slotL ^ rlo;
    const char* vgsrc = vtensor ? (const char*)Vtp : (const char*)Vtr;
    const char* vgp = vgsrc + base*2 + (size_t)(quarter*16 + rlo) * (CS*2)
                    + (size_t)kvbase*2 + chunkL*16;

    auto stageV = [&](int bi, int t) {
        const char* p = vgp + (size_t)t * 128;
        uint4* ld = &vstg[bi][vtensor][quarter * 128];
        #pragma unroll
        for (int i = 0; i < 2; ++i)
            gload16(p + (size_t)i * (8 * CS * 2), ld + i * 64);
    };

    stageV(0, 0);   // issue first V tile ASAP; prologue below overlaps it

    // Q fragments (B-operand: col=l16=q, k=ks*32+lhi*8+j)
    bf16x8 qrf[2], qpf[2];
    #pragma unroll
    for (int ks = 0; ks < 2; ++ks) {
        const size_t qoff = base + (size_t)(q0 + l16) * CDK + ks*32 + lhi*8;
        qrf[ks] = *reinterpret_cast<const bf16x8*>(&Qr[qoff]);
        qpf[ks] = *reinterpret_cast<const bf16x8*>(&Qp[qoff]);
    }

    // mask bitmap: per-lane 16 bits per KV tile, bit (kb*4+i) = key kb*16+lhi*4+i
    unsigned long long keepA[8] = {};
    for (int t = 0; t < nt; ++t) {
        const unsigned long long m64 =
            __ballot(mask[b*CS + kvbase + t*64 + lane] != 0);
        const unsigned long long s = m64 >> (lhi * 4);
        const unsigned int k16 = (unsigned int)(s & 0xFull)
                               | ((unsigned int)((s >> 16) & 0xFull) << 4)
                               | ((unsigned int)((s >> 32) & 0xFull) << 8)
                               | ((unsigned int)((s >> 48) & 0xFull) << 12);
        keepA[t >> 2] |= (unsigned long long)k16 << ((t & 3) * 16);
    }

    f32x4 oR[4] = {}, oP[4] = {};   // [dt]: O^T rows d=dt*16+lhi*4+i, col q=l16
    float lpart = 0.f;

    asm volatile("s_waitcnt vmcnt(0)" ::: "memory");
    __syncthreads();

    for (int t = 0; t < nt; ++t) {
        if (t + 1 < nt) stageV((t + 1) & 1, t + 1);

        const int kvg = kvbase + t * 64;
        const unsigned int k16 = (unsigned int)(keepA[t >> 2] >> ((t & 3) * 16)) & 0xFFFFu;

        // K loaded directly from global (L2); rolling 1-kb-ahead prefetch.
        const bf16* kbase_r = Kr + base + (size_t)kvg * CDK + lhi*8;
        const bf16* kbase_p = Kp + base + (size_t)kvg * CDK + lhi*8;
        bf16x8 krr[2][2], kpp[2][2];   // [parity][ks]
        #pragma unroll
        for (int ks = 0; ks < 2; ++ks) {
            krr[0][ks] = *reinterpret_cast<const bf16x8*>(kbase_r + (size_t)l16*CDK + ks*32);
            kpp[0][ks] = *reinterpret_cast<const bf16x8*>(kbase_p + (size_t)l16*CDK + ks*32);
        }

        float pp[4][4];
        #pragma unroll
        for (int kb = 0; kb < 4; ++kb) {
            if (kb < 3) {
                const size_t ro = (size_t)((kb + 1)*16 + l16) * CDK;
                #pragma unroll
                for (int ks = 0; ks < 2; ++ks) {
                    krr[(kb + 1) & 1][ks] = *reinterpret_cast<const bf16x8*>(kbase_r + ro + ks*32);
                    kpp[(kb + 1) & 1][ks] = *reinterpret_cast<const bf16x8*>(kbase_p + ro + ks*32);
                }
            }
            const int par = kb & 1;
            f32x4 aR = {}, aP = {};
            __builtin_amdgcn_s_setprio(1);
            #pragma unroll
            for (int ks = 0; ks < 2; ++ks) {
                const bf16x8 kr8 = krr[par][ks];
                const bf16x8 kp8 = kpp[par][ks];
                uint4 tn = __builtin_bit_cast(uint4, kp8);
                tn.x ^= 0x80008000u; tn.y ^= 0x80008000u;
                tn.z ^= 0x80008000u; tn.w ^= 0x80008000u;
                const bf16x8 kn8 = __builtin_bit_cast(bf16x8, tn);   // -kp exact
                aR = mfma16(kr8, qrf[ks], aR);
                aR = mfma16(kn8, qpf[ks], aR);
                aP = mfma16(kr8, qpf[ks], aP);
                aP = mfma16(kp8, qrf[ks], aP);
            }
            __builtin_amdgcn_s_setprio(0);
            #pragma unroll
            for (int i = 0; i < 4; ++i) {
                const float sr = aR[i], sp = aP[i];
                const float mag = __builtin_amdgcn_sqrtf(fmaf(sr, sr, sp*sp));
                float p = __builtin_amdgcn_exp2f(fmaf(mag, 0.18033688f, -5.77078016f));
                p = ((k16 >> (kb*4 + i)) & 1u) ? p : 0.0f;
                pp[kb][i] = p;
                lpart += p;
            }
        }

        // assemble P^T B-frags in-register (per 32-key block c) and run PV
        #pragma unroll
        for (int c = 0; c < 2; ++c) {
            unsigned int r0, r1, r2, r3;
            asm("v_cvt_pk_bf16_f32 %0, %1, %2" : "=v"(r0) : "v"(pp[2*c][0]),   "v"(pp[2*c][1]));
            asm("v_cvt_pk_bf16_f32 %0, %1, %2" : "=v"(r1) : "v"(pp[2*c][2]),   "v"(pp[2*c][3]));
            asm("v_cvt_pk_bf16_f32 %0, %1, %2" : "=v"(r2) : "v"(pp[2*c+1][0]), "v"(pp[2*c+1][1]));
            asm("v_cvt_pk_bf16_f32 %0, %1, %2" : "=v"(r3) : "v"(pp[2*c+1][2]), "v"(pp[2*c+1][3]));
            asm volatile("v_permlane32_swap_b32 %0, %1" : "+v"(r0), "+v"(r2));
            asm volatile("v_permlane32_swap_b32 %0, %1" : "+v"(r1), "+v"(r3));
            asm volatile("v_permlane16_swap_b32 %0, %1" : "+v"(r0), "+v"(r2));
            asm volatile("v_permlane16_swap_b32 %0, %1" : "+v"(r1), "+v"(r3));
            uint4 fw; fw.x = r0; fw.y = r1; fw.z = r2; fw.w = r3;
            const bf16x8 pa = __builtin_bit_cast(bf16x8, fw);
            __builtin_amdgcn_s_setprio(1);
            #pragma unroll
            for (int dt = 0; dt < 4; ++dt) {
                const int vrow = dt*16 + l16;
                const int ci = vrow*8 + ((c*4 + lhi) ^ (vrow & 7));
                const bf16x8 v8r = __builtin_bit_cast(bf16x8, vstg[t & 1][0][ci]);
                const bf16x8 v8p = __builtin_bit_cast(bf16x8, vstg[t & 1][1][ci]);
                oR[dt] = mfma16(v8r, pa, oR[dt]);
                oP[dt] = mfma16(v8p, pa, oP[dt]);
            }
            __builtin_amdgcn_s_setprio(0);
        }

        if (t + 1 < nt) __syncthreads();
    }

    // epilogue: l per-lane (one q per lane); reduce across lhi groups
    {
        float v = lpart;
        v += __shfl_xor(v, 16);
        v += __shfl_xor(v, 32);
        lpart = v;
    }
    const int r0q = bh * CS + q0;
    if (lane < 16)
        PLs[(size_t)z * NROWS + r0q + lane] = lpart;

    const size_t zo = (size_t)z * NROWS * 64;
    #pragma unroll
    for (int dt = 0; dt < 4; ++dt) {
        const size_t off = zo + (size_t)(r0q + l16) * 64 + dt*16 + lhi*4;
        *reinterpret_cast<f32x4*>(&POR[off]) = oR[dt];
        *reinterpret_cast<f32x4*>(&POP[off]) = oP[dt];
    }
}

// ---- combine KV-split partials, normalize, write [B,S,D] bf16 (x4 vectorized) ----
__global__ __launch_bounds__(256) void merge_kernel(
    const float* __restrict__ POR, const float* __restrict__ POP,
    const float* __restrict__ PLs, int nsp,
    bf16* __restrict__ Xr, bf16* __restrict__ Xp)
{
    const int idx = blockIdx.x * 256 + threadIdx.x;   // 0 .. NROWS*16-1
    const int r = idx >> 4, c0 = (idx & 15) * 4;
    float l = 0.f;
    f32x4 orv = {}, opv = {};
    for (int zz = 0; zz < nsp; ++zz) {
        l += PLs[(size_t)zz * NROWS + r];
        const size_t o = (size_t)zz * NROWS * 64 + (size_t)r * 64 + c0;
        orv += *reinterpret_cast<const f32x4*>(&POR[o]);
        opv += *reinterpret_cast<const f32x4*>(&POP[o]);
    }
    const float inv = 1.f / l;
    const int bh = r >> 11, q = r & 2047;
    const int b = bh >> 3, h = bh & 7;
    const size_t off = ((size_t)(b*CS + q)) * CD + h*CDK + c0;
    bf16 vr[4], vp[4];
    #pragma unroll
    for (int j = 0; j < 4; ++j) { vr[j] = (bf16)(orv[j]*inv); vp[j] = (bf16)(opv[j]*inv); }
    *reinterpret_cast<uint2*>(&Xr[off]) = *reinterpret_cast<const uint2*>(vr);
    *reinterpret_cast<uint2*>(&Xp[off]) = *reinterpret_cast<const uint2*>(vp);
}

extern "C" void kernel_launch(void* const* d_in, const int* in_sizes, int n_in,
                              void* d_out, int out_size, void* d_ws, size_t ws_size,
                              hipStream_t stream) {
    const float* q_r = (const float*)d_in[0];
    const float* k_r = (const float*)d_in[1];
    const float* v_r = (const float*)d_in[2];
    const float* q_p = (const float*)d_in[3];
    const float* k_p = (const float*)d_in[4];
    const float* v_p = (const float*)d_in[5];
    const int*  mask = (const int*)d_in[6];
    const float* Wq = (const float*)d_in[7];  const float* bq = (const float*)d_in[8];
    const float* Wk = (const float*)d_in[9];  const float* bk = (const float*)d_in[10];
    const float* Wv = (const float*)d_in[11]; const float* bv = (const float*)d_in[12];
    const float* Wo = (const float*)d_in[13]; const float* bo = (const float*)d_in[14];
    float* out = (float*)d_out;

    bf16* ws = (bf16*)d_ws;
    bf16* Abf = ws;                          // 6 * NT
    bf16* Wbf = ws + 6 * NT;                 // 4 * WN
    bf16* Qr  = Wbf + 4 * WN;
    bf16 *Qp = Qr + NT, *Kr = Qp + NT, *Kp = Kr + NT;
    bf16 *Vtr = Kp + NT, *Vtp = Vtr + NT;
    bf16 *Xr = Vtp + NT, *Xp = Xr + NT;
    float* POR = (float*)(Xp + NT);

    const size_t fixedB = (14 * NT + 4 * WN) * sizeof(bf16);
    const size_t per_split = (size_t)NROWS * 64 * 4 * 2 + (size_t)NROWS * 4;
    int nsp, lognsp;
    if (ws_size >= fixedB + 2 * per_split) { nsp = 2; lognsp = 1; }
    else                                   { nsp = 1; lognsp = 0; }
    float* POP = POR + (size_t)nsp * NROWS * 64;
    float* PLs = POP + (size_t)nsp * NROWS * 64;

    dim3 blk(256);

    // conversion pass
    CvtP C;
    C.src[0]=q_r; C.src[1]=q_p; C.src[2]=k_r; C.src[3]=k_p; C.src[4]=v_r; C.src[5]=v_p;
    C.src[6]=Wq;  C.src[7]=Wk;  C.src[8]=Wv;  C.src[9]=Wo;
    for (int i = 0; i < 6; ++i) { C.dst[i] = Abf + (size_t)i * NT; C.n8[i] = (int)(NT / 8); }
    for (int i = 0; i < 4; ++i) { C.dst[6+i] = Wbf + (size_t)i * WN; C.n8[6+i] = (int)(WN / 8); }
    cvt_kernel<<<dim3((unsigned)(NT / 8 / 256), 10), blk, 0, stream>>>(C);

    // projections
    PB P;
    for (int i = 0; i < 6; ++i) P.A[i] = Abf + (size_t)i * NT;
    P.W[0]=Wbf;      P.W[1]=Wbf;      P.W[2]=Wbf+WN;   P.W[3]=Wbf+WN;
    P.W[4]=Wbf+2*WN; P.W[5]=Wbf+2*WN;
    P.bias[0]=bq; P.bias[1]=bq; P.bias[2]=bk; P.bias[3]=bk; P.bias[4]=bv; P.bias[5]=bv;
    P.dst[0]=Qr; P.dst[1]=Qp; P.dst[2]=Kr; P.dst[3]=Kp; P.dst[4]=Vtr; P.dst[5]=Vtp;
    P.mode[0]=0; P.mode[1]=0; P.mode[2]=0; P.mode[3]=0; P.mode[4]=1; P.mode[5]=1;
    projb_kernel<<<dim3(64, 8, 6), blk, 0, stream>>>(P);

    attn_kernel<<<dim3(256 * nsp), dim3(512), 0, stream>>>(Qr, Qp, Kr, Kp, Vtr, Vtp,
                                                           mask, lognsp, POR, POP, PLs);

    merge_kernel<<<dim3(NROWS * 16 / 256), blk, 0, stream>>>(POR, POP, PLs, nsp, Xr, Xp);

    oprojb_kernel<<<dim3(64, 8, 2), blk, 0, stream>>>(Xr, Xp, Wbf + 3 * WN, bo, out);
}

// Round 12
// 122.048 us; speedup vs baseline: 1.6202x; 1.6202x over previous
//
#include <hip/hip_runtime.h>

typedef __bf16 bf16;
typedef __bf16 bf16x8 __attribute__((ext_vector_type(8)));
typedef float  f32x4  __attribute__((ext_vector_type(4)));

static constexpr int CB = 2;     // batch
static constexpr int CS = 2048;  // seq
static constexpr int CD = 512;   // model dim
static constexpr int CH = 8;     // heads
static constexpr int CDK = 64;   // head dim
static constexpr int NROWS = CB * CH * CS;         // 32768 attention rows
static constexpr size_t NT = (size_t)CB * CS * CD; // 2,097,152 elements per tensor
static constexpr size_t WN = (size_t)CD * CD;      // 262,144 weight elements

__device__ __forceinline__ f32x4 mfma16(bf16x8 a, bf16x8 b, f32x4 c) {
    return __builtin_amdgcn_mfma_f32_16x16x32_bf16(a, b, c, 0, 0, 0);
}

__device__ __forceinline__ bf16x8 cvt8(const float* __restrict__ p) {
    float4 x0 = *reinterpret_cast<const float4*>(p);
    float4 x1 = *reinterpret_cast<const float4*>(p + 4);
    bf16x8 r;
    r[0] = (bf16)x0.x; r[1] = (bf16)x0.y; r[2] = (bf16)x0.z; r[3] = (bf16)x0.w;
    r[4] = (bf16)x1.x; r[5] = (bf16)x1.y; r[6] = (bf16)x1.z; r[7] = (bf16)x1.w;
    return r;
}

__device__ __forceinline__ void gload16(const void* g, void* l) {
    __builtin_amdgcn_global_load_lds(
        (const __attribute__((address_space(1))) void*)g,
        (__attribute__((address_space(3))) void*)l, 16, 0, 0);
}

// ---- f32 -> bf16 conversion pass (inputs + weights) ----
struct CvtP {
    const float* src[10];
    bf16* dst[10];
    int n8[10];       // elements/8
};
__global__ __launch_bounds__(256) void cvt_kernel(CvtP C) {
    const int t = blockIdx.y;
    const int i = blockIdx.x * 256 + threadIdx.x;
    if (i < C.n8[t])
        *reinterpret_cast<bf16x8*>(C.dst[t] + (size_t)i * 8) =
            cvt8(C.src[t] + (size_t)i * 8);
}

// ---- merged projection GEMM (bf16 in), 128x128 tile, BK=32, gload_lds dbuf ----
// C[m,n] = sum_k A[m,k]*W[n,k] + bias[n]. M=4096, N=512, K=512. grid (32,4,6).
// LDS 32KB -> 3 blocks/CU (grid-limited). MFMA:ds_read = 2:1 per k-step.
struct PB {
    const bf16* A[6];
    const bf16* W[6];
    const float* bias[6];
    bf16* dst[6];
    int mode[6];   // 0: [B,H,S,DK]   1: [B,H,DK,S]
};
__global__ __launch_bounds__(256) void projb_kernel(PB P) {
    __shared__ uint4 tile[2][2][512];   // [buf][A/B][row*4+slot] 32KB, XOR-swizzled

    const int z = blockIdx.z;
    const bf16* __restrict__ A = P.A[z];
    const bf16* __restrict__ W = P.W[z];
    const float* __restrict__ bias = P.bias[z];
    bf16* __restrict__ dst = P.dst[z];
    const int mode = P.mode[z];

    const int m0 = blockIdx.x * 128, n0 = blockIdx.y * 128;
    const int tid = threadIdx.x;
    const int lane = tid & 63, w = tid >> 6;
    const int wr = w >> 1, wc = w & 1;
    const int l16 = lane & 15, lhi = lane >> 4;

    // staging: wave w -> tensor (w>>1), row half (w&1); rows of 32 bf16 (64B, 4 chunks)
    const int tensor = w >> 1, half = w & 1;
    const int rlo = lane >> 2, ch = lane & 3;        // 16 rows x 4 chunks per issue
    const bf16* gbase = tensor ? W : A;
    const int t0 = tensor ? n0 : m0;
    const char* gp = (const char*)gbase
                   + (size_t)(t0 + half*64 + rlo) * (CD * 2)
                   + (size_t)((ch ^ (rlo & 3)) * 16);

    auto stage = [&](int buf, int kk) {
        const char* p = gp + (size_t)kk * 64;        // 32 bf16 per k-step
        uint4* ld = &tile[buf][tensor][half * 256];
        #pragma unroll
        for (int i = 0; i < 4; ++i)
            gload16(p + (size_t)i * 16 * (CD * 2), ld + i * 64);
    };

    f32x4 acc[4][4] = {};

    stage(0, 0);
    asm volatile("s_waitcnt vmcnt(0)" ::: "memory");
    __syncthreads();

    for (int kk = 0; kk < 16; ++kk) {
        if (kk + 1 < 16) stage((kk + 1) & 1, kk + 1);

        const uint4* aT = &tile[kk & 1][0][0];
        const uint4* bT = &tile[kk & 1][1][0];
        bf16x8 af[4], bg[4];
        #pragma unroll
        for (int ms = 0; ms < 4; ++ms) {
            const int ra = wr*64 + ms*16 + l16;
            af[ms] = __builtin_bit_cast(bf16x8, aT[ra*4 + (lhi ^ (ra & 3))]);
        }
        #pragma unroll
        for (int ns = 0; ns < 4; ++ns) {
            const int rb = wc*64 + ns*16 + l16;
            bg[ns] = __builtin_bit_cast(bf16x8, bT[rb*4 + (lhi ^ (rb & 3))]);
        }
        #pragma unroll
        for (int ms = 0; ms < 4; ++ms)
            #pragma unroll
            for (int ns = 0; ns < 4; ++ns)
                acc[ms][ns] = mfma16(af[ms], bg[ns], acc[ms][ns]);

        if (kk + 1 < 16) __syncthreads();
    }

    #pragma unroll
    for (int ms = 0; ms < 4; ++ms)
    #pragma unroll
    for (int ns = 0; ns < 4; ++ns) {
        const int col = n0 + wc*64 + ns*16 + l16;
        const float bv = bias[col];
        const int hh = col >> 6, dk = col & 63;
        #pragma unroll
        for (int i = 0; i < 4; ++i) {
            const int m = m0 + wr*64 + ms*16 + lhi*4 + i;
            const float v = acc[ms][ns][i] + bv;
            const int b = m >> 11, s = m & 2047;
            if (mode == 0)
                dst[(((size_t)(b*CH + hh)) * CS + s) * CDK + dk] = (bf16)v;
            else
                dst[(((size_t)(b*CH + hh)) * CDK + dk) * CS + s] = (bf16)v;
        }
    }
}

// ---- output GEMM (bf16 in), 64x64 tile, gload_lds dbuf. grid (64,8,2). ----
__global__ __launch_bounds__(256) void oprojb_kernel(
    const bf16* __restrict__ Xr, const bf16* __restrict__ Xp,
    const bf16* __restrict__ Wo, const float* __restrict__ bo,
    float* __restrict__ out)
{
    __shared__ uint4 tile[2][2][512];

    const bf16* __restrict__ A = blockIdx.z ? Xp : Xr;
    float* __restrict__ dst = out + (size_t)blockIdx.z * NT;

    const int m0 = blockIdx.x * 64, n0 = blockIdx.y * 64;
    const int tid = threadIdx.x;
    const int lane = tid & 63, w = tid >> 6;
    const int wm = w >> 1, wn = w & 1;
    const int l16 = lane & 15, lhi = lane >> 4;

    const int tensor = w >> 1, half = w & 1;
    const int rlo = lane >> 3, slotL = lane & 7;
    const bf16* gbase = tensor ? Wo : A;
    const int t0 = tensor ? n0 : m0;
    const char* gp = (const char*)gbase
                   + (size_t)(t0 + half*32 + rlo) * (CD * 2)
                   + (size_t)((slotL ^ rlo) * 16);

    auto stage = [&](int buf, int kk) {
        const char* p = gp + (size_t)kk * 128;
        uint4* ld = &tile[buf][tensor][half * 256];
        #pragma unroll
        for (int i = 0; i < 4; ++i)
            gload16(p + (size_t)i * 8 * (CD * 2), ld + i * 64);
    };

    f32x4 acc[2][2] = {};

    stage(0, 0);
    asm volatile("s_waitcnt vmcnt(0)" ::: "memory");
    __syncthreads();

    for (int kk = 0; kk < 8; ++kk) {
        if (kk + 1 < 8) stage((kk + 1) & 1, kk + 1);

        const uint4* aT = &tile[kk & 1][0][0];
        const uint4* bT = &tile[kk & 1][1][0];
        #pragma unroll
        for (int ks = 0; ks < 2; ++ks) {
            const int c = ks*4 + lhi;
            const int ra0 = wm*32 + l16, ra1 = ra0 + 16;
            const int rb0 = wn*32 + l16, rb1 = rb0 + 16;
            bf16x8 af0 = __builtin_bit_cast(bf16x8, aT[ra0*8 + (c ^ (ra0 & 7))]);
            bf16x8 af1 = __builtin_bit_cast(bf16x8, aT[ra1*8 + (c ^ (ra1 & 7))]);
            bf16x8 bg0 = __builtin_bit_cast(bf16x8, bT[rb0*8 + (c ^ (rb0 & 7))]);
            bf16x8 bg1 = __builtin_bit_cast(bf16x8, bT[rb1*8 + (c ^ (rb1 & 7))]);
            acc[0][0] = mfma16(af0, bg0, acc[0][0]);
            acc[0][1] = mfma16(af0, bg1, acc[0][1]);
            acc[1][0] = mfma16(af1, bg0, acc[1][0]);
            acc[1][1] = mfma16(af1, bg1, acc[1][1]);
        }
        if (kk + 1 < 8) __syncthreads();
    }

    #pragma unroll
    for (int ms = 0; ms < 2; ++ms)
    #pragma unroll
    for (int ns = 0; ns < 2; ++ns) {
        const int col = n0 + wn*32 + ns*16 + l16;
        const float bv = bo[col];
        #pragma unroll
        for (int i = 0; i < 4; ++i) {
            const int m = m0 + wm*32 + ms*16 + lhi*4 + i;
            dst[(size_t)m * 512 + col] = acc[ms][ns][i] + bv;
        }
    }
}

// ---- flash attention (round-9 version, verbatim): 512 thr (8 waves), 16 q/wave,
// swapped QK^T, in-reg P via cvt_pk+permlane. KV tile 64, dbuf gload_lds, 64KB LDS.
__global__ __launch_bounds__(512, 4) void attn_kernel(
    const bf16* __restrict__ Qr, const bf16* __restrict__ Qp,
    const bf16* __restrict__ Kr, const bf16* __restrict__ Kp,
    const bf16* __restrict__ Vtr, const bf16* __restrict__ Vtp,
    const int* __restrict__ mask, int lognsp,
    float* __restrict__ POR, float* __restrict__ POP, float* __restrict__ PLs)
{
    __shared__ uint4 stg[2][4][512];   // [buf][tensor Kr,Kp,Vtr,Vtp][row*8+slot] 64KB

    const int F = blockIdx.x;
    const int qt = (F >> 3) & 15;
    const int g  = (F & 7) | ((F >> 7) << 3);     // (bh,z) groups pinned per XCD
    const int bh = g >> lognsp, z = g & ((1 << lognsp) - 1);
    const int Lkv = CS >> lognsp, kvbase = z * Lkv;
    const int nt = Lkv >> 6;
    const int b = bh >> 3;
    const size_t base = (size_t)bh * CS * CDK;

    const int tid = threadIdx.x, lane = tid & 63, w = tid >> 6;
    const int l16 = lane & 15, lhi = lane >> 4;
    const int q0 = qt * 128 + w * 16;

    // staging: wave w -> tensor w>>1, row half w&1 (4 gload16 per wave)
    const int tensor = w >> 1, half = w & 1;
    const int rlo = lane >> 3, slotL = lane & 7;
    const int chunkL = slotL ^ rlo;
    const char* gsrc = (tensor == 0) ? (const char*)Kr : (tensor == 1) ? (const char*)Kp
                     : (tensor == 2) ? (const char*)Vtr : (const char*)Vtp;
    size_t laneoff, iStride, tStride;
    if (tensor < 2) {
        laneoff = base*2 + (size_t)(kvbase + half*32 + rlo) * 128 + chunkL*16;
        iStride = 8 * 128;  tStride = 8192;
    } else {
        laneoff = base*2 + (size_t)(half*32 + rlo) * (CS*2) + (size_t)kvbase*2 + chunkL*16;
        iStride = 8 * CS * 2;  tStride = 128;
    }
    const char* gp = gsrc + laneoff;

    auto stage = [&](int bi, int t) {
        const char* p = gp + (size_t)t * tStride;
        uint4* ldst = &stg[bi][tensor][half * 256];
        #pragma unroll
        for (int i = 0; i < 4; ++i)
            gload16(p + i*iStride, ldst + i*64);
    };

    stage(0, 0);   // issue first tile ASAP; prologue work below overlaps it

    // Q fragments (B-operand: col=l16=q, k=ks*32+lhi*8+j), one 16-q subtile per wave
    bf16x8 qrf[2], qpf[2], qnf[2];
    #pragma unroll
    for (int ks = 0; ks < 2; ++ks) {
        const size_t qoff = base + (size_t)(q0 + l16) * CDK + ks*32 + lhi*8;
        qrf[ks] = *reinterpret_cast<const bf16x8*>(&Qr[qoff]);
        qpf[ks] = *reinterpret_cast<const bf16x8*>(&Qp[qoff]);
        uint4 t = __builtin_bit_cast(uint4, qpf[ks]);
        t.x ^= 0x80008000u; t.y ^= 0x80008000u; t.z ^= 0x80008000u; t.w ^= 0x80008000u;
        qnf[ks] = __builtin_bit_cast(bf16x8, t);   // -qp exact
    }

    // mask bitmap: per-lane 16 bits per KV tile, bit (kb*4+i) = key kb*16+lhi*4+i
    unsigned long long keepA[8] = {};
    for (int t = 0; t < nt; ++t) {
        const unsigned long long m64 =
            __ballot(mask[b*CS + kvbase + t*64 + lane] != 0);
        const unsigned long long s = m64 >> (lhi * 4);
        const unsigned int k16 = (unsigned int)(s & 0xFull)
                               | ((unsigned int)((s >> 16) & 0xFull) << 4)
                               | ((unsigned int)((s >> 32) & 0xFull) << 8)
                               | ((unsigned int)((s >> 48) & 0xFull) << 12);
        keepA[t >> 2] |= (unsigned long long)k16 << ((t & 3) * 16);
    }

    f32x4 oR[4] = {}, oP[4] = {};   // [dt]: O^T rows d=dt*16+lhi*4+i, col q=l16
    float lpart = 0.f;

    asm volatile("s_waitcnt vmcnt(0)" ::: "memory");
    __syncthreads();

    for (int t = 0; t < nt; ++t) {
        if (t + 1 < nt) stage((t + 1) & 1, t + 1);

        const int bi = t & 1;
        const unsigned int k16 = (unsigned int)(keepA[t >> 2] >> ((t & 3) * 16)) & 0xFFFFu;
        const uint4* kTr = &stg[bi][0][0];
        const uint4* kTp = &stg[bi][1][0];
        const uint4* vTr = &stg[bi][2][0];
        const uint4* vTp = &stg[bi][3][0];

        float pp[4][4];
        #pragma unroll
        for (int kb = 0; kb < 4; ++kb) {
            const int krow = kb*16 + l16;
            f32x4 aR = {}, aP = {};
            __builtin_amdgcn_s_setprio(1);
            #pragma unroll
            for (int ks = 0; ks < 2; ++ks) {
                const int ci = krow*8 + ((ks*4 + lhi) ^ (krow & 7));
                const bf16x8 kr8 = __builtin_bit_cast(bf16x8, kTr[ci]);
                const bf16x8 kp8 = __builtin_bit_cast(bf16x8, kTp[ci]);
                aR = mfma16(kr8, qrf[ks], aR);
                aR = mfma16(kp8, qnf[ks], aR);
                aP = mfma16(kr8, qpf[ks], aP);
                aP = mfma16(kp8, qrf[ks], aP);
            }
            __builtin_amdgcn_s_setprio(0);
            #pragma unroll
            for (int i = 0; i < 4; ++i) {
                const float sr = aR[i], sp = aP[i];
                const float mag = __builtin_amdgcn_sqrtf(fmaf(sr, sr, sp*sp));
                float p = __builtin_amdgcn_exp2f(fmaf(mag, 0.18033688f, -5.77078016f));
                p = ((k16 >> (kb*4 + i)) & 1u) ? p : 0.0f;
                pp[kb][i] = p;
                lpart += p;
            }
        }

        // assemble P^T B-frags in-register (per 32-key block c) and run PV
        #pragma unroll
        for (int c = 0; c < 2; ++c) {
            unsigned int r0, r1, r2, r3;
            asm("v_cvt_pk_bf16_f32 %0, %1, %2" : "=v"(r0) : "v"(pp[2*c][0]),   "v"(pp[2*c][1]));
            asm("v_cvt_pk_bf16_f32 %0, %1, %2" : "=v"(r1) : "v"(pp[2*c][2]),   "v"(pp[2*c][3]));
            asm("v_cvt_pk_bf16_f32 %0, %1, %2" : "=v"(r2) : "v"(pp[2*c+1][0]), "v"(pp[2*c+1][1]));
            asm("v_cvt_pk_bf16_f32 %0, %1, %2" : "=v"(r3) : "v"(pp[2*c+1][2]), "v"(pp[2*c+1][3]));
            asm volatile("v_permlane32_swap_b32 %0, %1" : "+v"(r0), "+v"(r2));
            asm volatile("v_permlane32_swap_b32 %0, %1" : "+v"(r1), "+v"(r3));
            asm volatile("v_permlane16_swap_b32 %0, %1" : "+v"(r0), "+v"(r2));
            asm volatile("v_permlane16_swap_b32 %0, %1" : "+v"(r1), "+v"(r3));
            uint4 fw; fw.x = r0; fw.y = r1; fw.z = r2; fw.w = r3;
            const bf16x8 pa = __builtin_bit_cast(bf16x8, fw);
            __builtin_amdgcn_s_setprio(1);
            #pragma unroll
            for (int dt = 0; dt < 4; ++dt) {
                const int vrow = dt*16 + l16;
                const int ci = vrow*8 + ((c*4 + lhi) ^ (vrow & 7));
                oR[dt] = mfma16(__builtin_bit_cast(bf16x8, vTr[ci]), pa, oR[dt]);
                oP[dt] = mfma16(__builtin_bit_cast(bf16x8, vTp[ci]), pa, oP[dt]);
            }
            __builtin_amdgcn_s_setprio(0);
        }

        if (t + 1 < nt) __syncthreads();
    }

    // epilogue: l per-lane (one q per lane); reduce across lhi groups
    {
        float v = lpart;
        v += __shfl_xor(v, 16);
        v += __shfl_xor(v, 32);
        lpart = v;
    }
    const int r0q = bh * CS + q0;
    if (lane < 16)
        PLs[(size_t)z * NROWS + r0q + lane] = lpart;

    const size_t zo = (size_t)z * NROWS * 64;
    #pragma unroll
    for (int dt = 0; dt < 4; ++dt) {
        const size_t off = zo + (size_t)(r0q + l16) * 64 + dt*16 + lhi*4;
        *reinterpret_cast<f32x4*>(&POR[off]) = oR[dt];
        *reinterpret_cast<f32x4*>(&POP[off]) = oP[dt];
    }
}

// ---- combine KV-split partials, normalize, write [B,S,D] bf16 (x4 vectorized) ----
__global__ __launch_bounds__(256) void merge_kernel(
    const float* __restrict__ POR, const float* __restrict__ POP,
    const float* __restrict__ PLs, int nsp,
    bf16* __restrict__ Xr, bf16* __restrict__ Xp)
{
    const int idx = blockIdx.x * 256 + threadIdx.x;   // 0 .. NROWS*16-1
    const int r = idx >> 4, c0 = (idx & 15) * 4;
    float l = 0.f;
    f32x4 orv = {}, opv = {};
    for (int zz = 0; zz < nsp; ++zz) {
        l += PLs[(size_t)zz * NROWS + r];
        const size_t o = (size_t)zz * NROWS * 64 + (size_t)r * 64 + c0;
        orv += *reinterpret_cast<const f32x4*>(&POR[o]);
        opv += *reinterpret_cast<const f32x4*>(&POP[o]);
    }
    const float inv = 1.f / l;
    const int bh = r >> 11, q = r & 2047;
    const int b = bh >> 3, h = bh & 7;
    const size_t off = ((size_t)(b*CS + q)) * CD + h*CDK + c0;
    bf16 vr[4], vp[4];
    #pragma unroll
    for (int j = 0; j < 4; ++j) { vr[j] = (bf16)(orv[j]*inv); vp[j] = (bf16)(opv[j]*inv); }
    *reinterpret_cast<uint2*>(&Xr[off]) = *reinterpret_cast<const uint2*>(vr);
    *reinterpret_cast<uint2*>(&Xp[off]) = *reinterpret_cast<const uint2*>(vp);
}

extern "C" void kernel_launch(void* const* d_in, const int* in_sizes, int n_in,
                              void* d_out, int out_size, void* d_ws, size_t ws_size,
                              hipStream_t stream) {
    const float* q_r = (const float*)d_in[0];
    const float* k_r = (const float*)d_in[1];
    const float* v_r = (const float*)d_in[2];
    const float* q_p = (const float*)d_in[3];
    const float* k_p = (const float*)d_in[4];
    const float* v_p = (const float*)d_in[5];
    const int*  mask = (const int*)d_in[6];
    const float* Wq = (const float*)d_in[7];  const float* bq = (const float*)d_in[8];
    const float* Wk = (const float*)d_in[9];  const float* bk = (const float*)d_in[10];
    const float* Wv = (const float*)d_in[11]; const float* bv = (const float*)d_in[12];
    const float* Wo = (const float*)d_in[13]; const float* bo = (const float*)d_in[14];
    float* out = (float*)d_out;

    bf16* ws = (bf16*)d_ws;
    bf16* Abf = ws;                          // 6 * NT
    bf16* Wbf = ws + 6 * NT;                 // 4 * WN
    bf16* Qr  = Wbf + 4 * WN;
    bf16 *Qp = Qr + NT, *Kr = Qp + NT, *Kp = Kr + NT;
    bf16 *Vtr = Kp + NT, *Vtp = Vtr + NT;
    bf16 *Xr = Vtp + NT, *Xp = Xr + NT;
    float* POR = (float*)(Xp + NT);

    const size_t fixedB = (14 * NT + 4 * WN) * sizeof(bf16);
    const size_t per_split = (size_t)NROWS * 64 * 4 * 2 + (size_t)NROWS * 4;
    int nsp, lognsp;
    if (ws_size >= fixedB + 2 * per_split) { nsp = 2; lognsp = 1; }
    else                                   { nsp = 1; lognsp = 0; }
    float* POP = POR + (size_t)nsp * NROWS * 64;
    float* PLs = POP + (size_t)nsp * NROWS * 64;

    dim3 blk(256);

    // conversion pass
    CvtP C;
    C.src[0]=q_r; C.src[1]=q_p; C.src[2]=k_r; C.src[3]=k_p; C.src[4]=v_r; C.src[5]=v_p;
    C.src[6]=Wq;  C.src[7]=Wk;  C.src[8]=Wv;  C.src[9]=Wo;
    for (int i = 0; i < 6; ++i) { C.dst[i] = Abf + (size_t)i * NT; C.n8[i] = (int)(NT / 8); }
    for (int i = 0; i < 4; ++i) { C.dst[6+i] = Wbf + (size_t)i * WN; C.n8[6+i] = (int)(WN / 8); }
    cvt_kernel<<<dim3((unsigned)(NT / 8 / 256), 10), blk, 0, stream>>>(C);

    // projections (128x128 tiles)
    PB P;
    for (int i = 0; i < 6; ++i) P.A[i] = Abf + (size_t)i * NT;
    P.W[0]=Wbf;      P.W[1]=Wbf;      P.W[2]=Wbf+WN;   P.W[3]=Wbf+WN;
    P.W[4]=Wbf+2*WN; P.W[5]=Wbf+2*WN;
    P.bias[0]=bq; P.bias[1]=bq; P.bias[2]=bk; P.bias[3]=bk; P.bias[4]=bv; P.bias[5]=bv;
    P.dst[0]=Qr; P.dst[1]=Qp; P.dst[2]=Kr; P.dst[3]=Kp; P.dst[4]=Vtr; P.dst[5]=Vtp;
    P.mode[0]=0; P.mode[1]=0; P.mode[2]=0; P.mode[3]=0; P.mode[4]=1; P.mode[5]=1;
    projb_kernel<<<dim3(32, 4, 6), blk, 0, stream>>>(P);

    attn_kernel<<<dim3(256 * nsp), dim3(512), 0, stream>>>(Qr, Qp, Kr, Kp, Vtr, Vtp,
                                                           mask, lognsp, POR, POP, PLs);

    merge_kernel<<<dim3(NROWS * 16 / 256), blk, 0, stream>>>(POR, POP, PLs, nsp, Xr, Xp);

    oprojb_kernel<<<dim3(64, 8, 2), blk, 0, stream>>>(Xr, Xp, Wbf + 3 * WN, bo, out);
}